// Round 3
// baseline (2792.980 us; speedup 1.0000x reference)
//
#include <hip/hip_runtime.h>
#include <math.h>

// Problem constants (match reference)
#define BATCH    8
#define NFFT     1024
#define HOPSZ    256
#define NBINS    513        // NFFT/2 + 1
#define SROW     516        // padded row stride (elements) for spec/mag/rebprev rows
#define TFRAMES  1024       // frames per batch (== T)
#define NBLK     (BATCH * TFRAMES)     // 8192 rows
#define LOUT     261888     // HOP*(T-1) : audio length per batch
#define YLEN     262912     // NFFT + HOP*(TFRAMES-1)
#define NITER    32

// Fused-kernel geometry
#define FR       16                      // output frames per block
#define HALO     3                       // OA halo frames each side
#define NIF      (FR + 2 * HALO)         // 22 iffts per block
#define OAW      ((FR - 1) * HOPSZ + NFFT)  // 4864 OA samples per block
#define GLW      8                       // waves per block

// LDS skew: physical = i + i/32 → breaks power-of-2 stride bank conflicts
#define LDSIDX(i) ((i) + ((i) >> 5))
#define LDSBUF    532       // LDSIDX(512)=528 → 529 needed

// Wave-local LDS sync: same-wave DS ops execute in order; this is what
// __syncthreads lowers to for single-wave workgroups (validated round 2).
__device__ __forceinline__ void wsync() {
    __asm__ volatile("s_waitcnt lgkmcnt(0)" ::: "memory");
}

// ---------------------------------------------------------------------------
// 8-point DFT in registers. SIGN=-1 forward, +1 inverse (unscaled).
// ---------------------------------------------------------------------------
template <int SIGN>
__device__ __forceinline__ void dft8(const float xr[8], const float xi[8],
                                     float yr[8], float yi[8])
{
    const float r2 = 0.70710678118654752f;
    float Ar = xr[0] + xr[4], Ai = xi[0] + xi[4];
    float Br = xr[0] - xr[4], Bi = xi[0] - xi[4];
    float Cr = xr[2] + xr[6], Ci = xi[2] + xi[6];
    float Dr = xr[2] - xr[6], Di = xi[2] - xi[6];
    float E0r = Ar + Cr, E0i = Ai + Ci;
    float E2r = Ar - Cr, E2i = Ai - Ci;
    float E1r, E1i, E3r, E3i;
    if (SIGN < 0) { E1r = Br + Di; E1i = Bi - Dr; E3r = Br - Di; E3i = Bi + Dr; }
    else          { E1r = Br - Di; E1i = Bi + Dr; E3r = Br + Di; E3i = Bi - Dr; }
    float ar = xr[1] + xr[5], ai = xi[1] + xi[5];
    float br = xr[1] - xr[5], bi = xi[1] - xi[5];
    float cr = xr[3] + xr[7], ci = xi[3] + xi[7];
    float dr = xr[3] - xr[7], di = xi[3] - xi[7];
    float O0r = ar + cr, O0i = ai + ci;
    float O2r = ar - cr, O2i = ai - ci;
    float O1r, O1i, O3r, O3i;
    if (SIGN < 0) { O1r = br + di; O1i = bi - dr; O3r = br - di; O3i = bi + dr; }
    else          { O1r = br - di; O1i = bi + dr; O3r = br + di; O3i = bi - dr; }
    float t1r, t1i, t2r, t2i, t3r, t3i;
    if (SIGN < 0) {
        t1r = r2 * (O1r + O1i); t1i = r2 * (O1i - O1r);
        t2r = O2i;              t2i = -O2r;
        t3r = r2 * (O3i - O3r); t3i = -r2 * (O3r + O3i);
    } else {
        t1r = r2 * (O1r - O1i); t1i = r2 * (O1i + O1r);
        t2r = -O2i;             t2i = O2r;
        t3r = -r2 * (O3r + O3i); t3i = r2 * (O3r - O3i);
    }
    yr[0] = E0r + O0r; yi[0] = E0i + O0i;  yr[4] = E0r - O0r; yi[4] = E0i - O0i;
    yr[1] = E1r + t1r; yi[1] = E1i + t1i;  yr[5] = E1r - t1r; yi[5] = E1i - t1i;
    yr[2] = E2r + t2r; yi[2] = E2i + t2i;  yr[6] = E2r - t2r; yi[6] = E2i - t2i;
    yr[3] = E3r + t3r; yi[3] = E3i + t3i;  yr[7] = E3r - t3r; yi[7] = E3i - t3i;
}

template <int SIGN, int S>
__device__ __forceinline__ void stage_write(float* lre, float* lim,
                                            const float yr[8], const float yi[8],
                                            int lane, const float2* __restrict__ tw)
{
    const int q = lane & (S - 1);
    const int p = lane / S;
    const int e = p * S;
    const int base = q + 8 * S * p;
#pragma unroll
    for (int j = 0; j < 8; ++j) {
        float vr = yr[j], vi = yi[j];
        if (j > 0) {
            float2 w = tw[j * e];
            float wr = w.x, wi = (SIGN < 0) ? w.y : -w.y;
            float tr = vr * wr - vi * wi;
            vi = vr * wi + vi * wr;
            vr = tr;
        }
        int o = LDSIDX(base + S * j);
        lre[o] = vr; lim[o] = vi;
    }
}

__device__ __forceinline__ void stage_read(const float* lre, const float* lim,
                                           float xr[8], float xi[8], int lane)
{
#pragma unroll
    for (int j = 0; j < 8; ++j) {
        int o = LDSIDX(lane + 64 * j);
        xr[j] = lre[o]; xi[j] = lim[o];
    }
}

// 512-pt FFT, 3 radix-8 stages, in-place per-wave LDS scratch, wave-local sync.
template <int SIGN>
__device__ __forceinline__ void fft512(float* lre, float* lim,
                                       float xr[8], float xi[8],
                                       float yr[8], float yi[8],
                                       int lane, const float2* __restrict__ tw)
{
    dft8<SIGN>(xr, xi, yr, yi);
    stage_write<SIGN, 1>(lre, lim, yr, yi, lane, tw);
    wsync();
    stage_read(lre, lim, xr, xi, lane);
    wsync();
    dft8<SIGN>(xr, xi, yr, yi);
    stage_write<SIGN, 8>(lre, lim, yr, yi, lane, tw);
    wsync();
    stage_read(lre, lim, xr, xi, lane);
    dft8<SIGN>(xr, xi, yr, yi);           // stage2: p=0 → no twiddles, stays in regs
}

// Load spec row (NBINS float2) into scratch, Hermitian pre-twist → stage0 regs.
__device__ __forceinline__ void load_spec_twist(const float2* __restrict__ specrow,
                                                float* lre, float* lim,
                                                const float2* __restrict__ twh,
                                                int lane, float xr[8], float xi[8])
{
#pragma unroll
    for (int rr = 0; rr < 8; ++rr) {
        int k = lane + 64 * rr;
        float2 v = specrow[k];
        if (k == 0) v.y = 0.f;
        lre[LDSIDX(k)] = v.x; lim[LDSIDX(k)] = v.y;
    }
    if (lane == 0) {
        float2 v = specrow[512];
        lre[LDSIDX(512)] = v.x; lim[LDSIDX(512)] = 0.f;
    }
    wsync();
#pragma unroll
    for (int rr = 0; rr < 8; ++rr) {
        int k = lane + 64 * rr, m = 512 - k;
        int ok = LDSIDX(k), om = LDSIDX(m);
        float Xkr = lre[ok], Xki = lim[ok];
        float Xmr = lre[om], Xmi = lim[om];
        float Ar = 0.5f * (Xkr + Xmr), Ai = 0.5f * (Xki - Xmi);
        float Sr = 0.5f * (Xkr - Xmr), Si = 0.5f * (Xki + Xmi);
        float2 W = twh[k];
        float Xor = W.x * Sr + W.y * Si;
        float Xoi = W.x * Si - W.y * Sr;
        xr[rr] = Ar - Xoi;
        xi[rr] = Ai + Xor;
    }
    wsync();
}

// ---------------------------------------------------------------------------
// Tables
// ---------------------------------------------------------------------------
__global__ void k_tables(float2* tw512, float2* twh, float* win, float* wscl)
{
    int i = blockIdx.x * blockDim.x + threadIdx.x;
    if (i < 512) {
        double t1 = -2.0 * M_PI * (double)i / 512.0;
        tw512[i] = make_float2((float)cos(t1), (float)sin(t1));
        double t2 = -2.0 * M_PI * (double)i / 1024.0;
        twh[i] = make_float2((float)cos(t2), (float)sin(t2));
    }
    if (i < 1024) {
        double w = 0.5 - 0.5 * cos(2.0 * M_PI * (double)i / 1024.0);
        win[i]  = (float)w;
        wscl[i] = (float)(w / 512.0);
    }
}

__global__ void k_wsq(const float* __restrict__ win, float* __restrict__ wsqinv)
{
    int t = blockIdx.x * blockDim.x + threadIdx.x;
    if (t >= YLEN) return;
    int fhi = t >> 8;
    int flo = fhi - 3; if (flo < 0) flo = 0;
    if (fhi > TFRAMES - 1) fhi = TFRAMES - 1;
    float acc = 0.f;
    for (int f = flo; f <= fhi; ++f) {
        float w = win[t - (f << 8)];
        acc += w * w;
    }
    float m = acc > 1e-8f ? acc : 1e-8f;
    wsqinv[t] = 1.0f / m;
}

__global__ void k_melinvT(const float* __restrict__ melinv, float* __restrict__ melinvT)
{
    int idx = blockIdx.x * blockDim.x + threadIdx.x;
    if (idx >= 80 * NBINS) return;
    int m = idx / NBINS, k = idx - m * NBINS;
    melinvT[idx] = melinv[k * 80 + m];
}

__global__ __launch_bounds__(256) void k_angT(const float* __restrict__ ang0,
                                              float* __restrict__ angT)
{
    __shared__ float tile[32][33];
    int kt = blockIdx.x * 32, tt = blockIdx.y * 32, b = blockIdx.z;
    int tx = threadIdx.x & 31, ty = threadIdx.x >> 5;
#pragma unroll
    for (int i = 0; i < 32; i += 8) {
        int k = kt + ty + i, t = tt + tx;
        if (k < NBINS) tile[ty + i][tx] = ang0[((size_t)b * NBINS + k) * 1024 + t];
    }
    __syncthreads();
#pragma unroll
    for (int i = 0; i < 32; i += 8) {
        int t = tt + ty + i, k = kt + tx;
        if (k < NBINS) angT[((size_t)b * 1024 + t) * NBINS + k] = tile[tx][ty + i];
    }
}

__global__ __launch_bounds__(256) void k_specinit(const float* __restrict__ mel,
                                                  const float* __restrict__ melinvT,
                                                  const float* __restrict__ angT,
                                                  float* __restrict__ mag,
                                                  float2* __restrict__ spec)
{
    int blk = blockIdx.x;
    int b = blk >> 10;
    int t = blk & 1023;
    int tid = threadIdx.x;
    __shared__ float em[80];
    if (tid < 80) em[tid] = expf(mel[((size_t)b * 80 + tid) * 1024 + t]);
    __syncthreads();
    size_t row = (size_t)blk * SROW;
    size_t arow = ((size_t)b * 1024 + t) * NBINS;
    for (int k = tid; k < NBINS; k += 256) {
        float s = 0.f;
#pragma unroll 8
        for (int m = 0; m < 80; ++m) s += melinvT[m * NBINS + k] * em[m];
        float mg = fabsf(s);
        float a = angT[arow + k];
        float sn, cn;
        sincospif(2.0f * a, &sn, &cn);
        mag[row + k] = mg;
        spec[row + k] = make_float2(mg * cn, mg * sn);
    }
}

// ---------------------------------------------------------------------------
// Fused GL iteration: ISTFT(22 rows incl. halo) → LDS overlap-add → STFT(16)
// + phase update. specin/specout ping-pong (cross-block halo reads must see
// the previous iteration's values).
// ---------------------------------------------------------------------------
__global__ __launch_bounds__(512, 4) void k_gl(const float2* __restrict__ specin,
                                               float2* __restrict__ specout,
                                               const float* __restrict__ mag,
                                               float2* __restrict__ rebprev,
                                               const float2* __restrict__ tw512,
                                               const float2* __restrict__ twh,
                                               const float* __restrict__ wscl,
                                               const float* __restrict__ win,
                                               const float* __restrict__ wsqinv,
                                               float beta)
{
    __shared__ float oa[OAW];
    __shared__ float scr[GLW][2][LDSBUF];
    int tid = threadIdx.x;
    int w = tid >> 6, lane = tid & 63;
    int b = blockIdx.x >> 6;              // 64 frame-groups per batch
    int f0 = (blockIdx.x & 63) * FR;
    int t0 = f0 * HOPSZ;

    for (int i = tid; i < OAW; i += 512) oa[i] = 0.f;
    __syncthreads();

    float* lre = scr[w][0];
    float* lim = scr[w][1];

    // ---- Phase 1: ifft frames f0-3 .. f0+18, accumulate windowed into oa ----
    for (int fi = w; fi < NIF; fi += GLW) {
        int ff = f0 - HALO + fi;
        if (ff < 0 || ff > TFRAMES - 1) continue;
        size_t row = ((size_t)b * TFRAMES + ff) * SROW;
        float xr[8], xi[8], yr[8], yi[8];
        load_spec_twist(specin + row, lre, lim, twh, lane, xr, xi);
        fft512<1>(lre, lim, xr, xi, yr, yi, lane, tw512);
        int base = ff * HOPSZ - t0;
#pragma unroll
        for (int j = 0; j < 8; ++j) {
            int m = lane + 64 * j;
            int i0 = base + 2 * m;               // even; i0,i0+1 same side of cut
            if (i0 >= 0 && i0 < OAW) {
                float2 ws = *(const float2*)&wscl[2 * m];
                atomicAdd(&oa[i0],     yr[j] * ws.x);
                atomicAdd(&oa[i0 + 1], yi[j] * ws.y);
            }
        }
    }
    __syncthreads();

    // ---- Phase 2: re-window from oa, forward FFT, GL phase update ----
    for (int r = 0; r < FR / GLW; ++r) {
        int f = f0 + w + GLW * r;
        float xr[8], xi[8], yr[8], yi[8];
#pragma unroll
        for (int j = 0; j < 8; ++j) {
            int m = lane + 64 * j;
            int n0 = 2 * m;
            int j0 = f * HOPSZ + n0 - 512;
            int ja = (j0 < 0) ? -j0 : ((j0 >= LOUT) ? 2 * LOUT - 2 - j0 : j0);
            int j1 = j0 + 1;
            int jb = (j1 < 0) ? -j1 : ((j1 >= LOUT) ? 2 * LOUT - 2 - j1 : j1);
            int ta = ja + 512, tb = jb + 512;
            float s0 = oa[ta - t0] * wsqinv[ta];
            float s1 = oa[tb - t0] * wsqinv[tb];
            float2 w2 = *(const float2*)&win[n0];
            xr[j] = s0 * w2.x;
            xi[j] = s1 * w2.y;
        }
        fft512<-1>(lre, lim, xr, xi, yr, yi, lane, tw512);
#pragma unroll
        for (int j = 0; j < 8; ++j) {
            int o = LDSIDX(lane + 64 * j);
            lre[o] = yr[j]; lim[o] = yi[j];
        }
        wsync();
        size_t row = ((size_t)b * TFRAMES + f) * SROW;
#pragma unroll
        for (int rr = 0; rr < 9; ++rr) {
            int k;
            if (rr < 8) k = lane + 64 * rr;
            else { if (lane != 0) break; k = 512; }
            int kk = k & 511, mm = (512 - k) & 511;
            float Zkr = lre[LDSIDX(kk)], Zki = lim[LDSIDX(kk)];
            float Zmr = lre[LDSIDX(mm)], Zmi = lim[LDSIDX(mm)];
            float Ar = 0.5f * (Zkr + Zmr), Ai = 0.5f * (Zki - Zmi);
            float Sr = 0.5f * (Zkr - Zmr), Si = 0.5f * (Zki + Zmi);
            float wr_, wi_;
            if (k == 512) { wr_ = -1.f; wi_ = 0.f; }
            else { float2 W = twh[k]; wr_ = W.x; wi_ = W.y; }
            float Ur = wr_ * Sr - wi_ * Si;
            float Ui = wr_ * Si + wi_ * Sr;
            float Xr = Ar + Ui;
            float Xi = Ai - Ur;
            float2 pv = rebprev[row + k];
            float vx = Xr - beta * pv.x;
            float vy = Xi - beta * pv.y;
            float a = sqrtf(vx * vx + vy * vy) + 1e-16f;
            float sc = mag[row + k] / a;
            specout[row + k] = make_float2(vx * sc, vy * sc);
            rebprev[row + k] = make_float2(Xr, Xi);
        }
        wsync();   // post-twist reads done before next round's stage writes
    }
}

// ---------------------------------------------------------------------------
// Final ISTFT half (frames) + gather
// ---------------------------------------------------------------------------
__global__ __launch_bounds__(64) void k_ifft(const float2* __restrict__ spec,
                                             const float2* __restrict__ tw512,
                                             const float2* __restrict__ twh,
                                             const float* __restrict__ wscl,
                                             float* __restrict__ frames)
{
    __shared__ float lre[LDSBUF], lim[LDSBUF];
    int blk = blockIdx.x;
    int lane = threadIdx.x;
    size_t row = (size_t)blk * SROW;
    float xr[8], xi[8], yr[8], yi[8];
    load_spec_twist(spec + row, lre, lim, twh, lane, xr, xi);
    fft512<1>(lre, lim, xr, xi, yr, yi, lane, tw512);
    size_t frow = (size_t)blk * 1024;
#pragma unroll
    for (int j = 0; j < 8; ++j) {
        int m = lane + 64 * j;
        float2 ws = *(const float2*)&wscl[2 * m];
        float2 o;
        o.x = yr[j] * ws.x;
        o.y = yi[j] * ws.y;
        *(float2*)&frames[frow + 2 * m] = o;
    }
}

__global__ __launch_bounds__(256) void k_gather(const float* __restrict__ frames,
                                                const float* __restrict__ wsqinv,
                                                float* __restrict__ out)
{
    int idx = blockIdx.x * 256 + threadIdx.x;
    if (idx >= BATCH * LOUT) return;
    int b = idx / LOUT;
    int j = idx - b * LOUT;
    int t = j + 512;
    const float* fb = frames + (size_t)b * (TFRAMES * 1024);
    int fhi = t >> 8;
    int flo = fhi - 3; if (flo < 0) flo = 0;
    if (fhi > TFRAMES - 1) fhi = TFRAMES - 1;
    float acc = 0.f;
    for (int ff = flo; ff <= fhi; ++ff)
        acc += fb[(size_t)ff * 1024 + (t - (ff << 8))];
    out[idx] = acc * wsqinv[t];
}

// ---------------------------------------------------------------------------
extern "C" void kernel_launch(void* const* d_in, const int* in_sizes, int n_in,
                              void* d_out, int out_size, void* d_ws, size_t ws_size,
                              hipStream_t stream)
{
    const float* mel    = (const float*)d_in[0];   // [8, 80, 1024]
    const float* melinv = (const float*)d_in[1];   // [513, 80]
    const float* ang0   = (const float*)d_in[2];   // [8, 513, 1024]
    float* out = (float*)d_out;                    // [8, 261888]

    char* ws = (char*)d_ws;
    size_t off = 0;
    auto carve = [&](size_t bytes) -> void* {
        void* p = ws + off;
        off += (bytes + 255) & ~(size_t)255;
        return p;
    };
    float2* tw512   = (float2*)carve(512 * sizeof(float2));
    float2* twh     = (float2*)carve(512 * sizeof(float2));
    float*  win     = (float*) carve(1024 * sizeof(float));
    float*  wscl    = (float*) carve(1024 * sizeof(float));
    float*  wsqinv  = (float*) carve((size_t)YLEN * sizeof(float));
    float*  melinvT = (float*) carve((size_t)80 * NBINS * sizeof(float));
    float*  mag     = (float*) carve((size_t)NBLK * SROW * sizeof(float));
    float2* spec0   = (float2*)carve((size_t)NBLK * SROW * sizeof(float2));
    float2* spec1   = (float2*)carve((size_t)NBLK * SROW * sizeof(float2));
    float2* rebp    = (float2*)carve((size_t)NBLK * SROW * sizeof(float2));
    // frames & angT alias spec1: angT consumed by k_specinit before iter 0
    // writes spec1; frames only written after the loop (final spec in spec0).
    float* frames = (float*)spec1;
    float* angT   = (float*)spec1;
    (void)ws_size; (void)in_sizes; (void)n_in; (void)out_size;

    const float beta = (float)(0.99 / 1.99);

    hipLaunchKernelGGL(k_tables, dim3(4), dim3(256), 0, stream, tw512, twh, win, wscl);
    hipLaunchKernelGGL(k_wsq, dim3((YLEN + 255) / 256), dim3(256), 0, stream, win, wsqinv);
    hipLaunchKernelGGL(k_melinvT, dim3((80 * NBINS + 255) / 256), dim3(256), 0, stream,
                       melinv, melinvT);
    hipLaunchKernelGGL(k_angT, dim3(17, 32, BATCH), dim3(256), 0, stream, ang0, angT);
    hipLaunchKernelGGL(k_specinit, dim3(NBLK), dim3(256), 0, stream,
                       mel, melinvT, angT, mag, spec0);
    (void)hipMemsetAsync(rebp, 0, (size_t)NBLK * SROW * sizeof(float2), stream);

    for (int it = 0; it < NITER; ++it) {
        const float2* sin_ = (it & 1) ? spec1 : spec0;
        float2*       sout = (it & 1) ? spec0 : spec1;
        hipLaunchKernelGGL(k_gl, dim3(BATCH * (TFRAMES / FR)), dim3(512), 0, stream,
                           sin_, sout, mag, rebp, tw512, twh, wscl, win, wsqinv, beta);
    }
    // NITER even → final spectrum in spec0
    hipLaunchKernelGGL(k_ifft, dim3(NBLK), dim3(64), 0, stream,
                       spec0, tw512, twh, wscl, frames);
    hipLaunchKernelGGL(k_gather, dim3((BATCH * LOUT + 255) / 256), dim3(256), 0, stream,
                       frames, wsqinv, out);
}

// Round 4
// 2101.497 us; speedup vs baseline: 1.3290x; 1.3290x over previous
//
#include <hip/hip_runtime.h>
#include <math.h>

// Problem constants (match reference)
#define BATCH    8
#define NFFT     1024
#define HOPSZ    256
#define NBINS    513        // NFFT/2 + 1
#define SROW     516        // padded row stride (elements) for spec/mag/rebprev rows
#define TFRAMES  1024       // frames per batch (== T)
#define NBLK     (BATCH * TFRAMES)     // 8192 rows
#define LOUT     261888     // HOP*(T-1) : audio length per batch
#define YLEN     262912     // NFFT + HOP*(TFRAMES-1) = 1027*256
#define NITER    32

// LDS skew: physical = i + i/32 → breaks power-of-2 stride bank conflicts
#define LDSIDX(i) ((i) + ((i) >> 5))
#define LDSBUF    532       // LDSIDX(511)+1 and headroom

// Wave-local LDS sync: same-wave DS ops execute in order; all FFT scratch is
// per-wave, so a full barrier is never needed (validated rounds 2-3).
__device__ __forceinline__ void wsync() {
    __asm__ volatile("s_waitcnt lgkmcnt(0)" ::: "memory");
}

// ---------------------------------------------------------------------------
// 8-point DFT in registers. SIGN=-1 forward, +1 inverse (unscaled).
// ---------------------------------------------------------------------------
template <int SIGN>
__device__ __forceinline__ void dft8(const float xr[8], const float xi[8],
                                     float yr[8], float yi[8])
{
    const float r2 = 0.70710678118654752f;
    float Ar = xr[0] + xr[4], Ai = xi[0] + xi[4];
    float Br = xr[0] - xr[4], Bi = xi[0] - xi[4];
    float Cr = xr[2] + xr[6], Ci = xi[2] + xi[6];
    float Dr = xr[2] - xr[6], Di = xi[2] - xi[6];
    float E0r = Ar + Cr, E0i = Ai + Ci;
    float E2r = Ar - Cr, E2i = Ai - Ci;
    float E1r, E1i, E3r, E3i;
    if (SIGN < 0) { E1r = Br + Di; E1i = Bi - Dr; E3r = Br - Di; E3i = Bi + Dr; }
    else          { E1r = Br - Di; E1i = Bi + Dr; E3r = Br + Di; E3i = Bi - Dr; }
    float ar = xr[1] + xr[5], ai = xi[1] + xi[5];
    float br = xr[1] - xr[5], bi = xi[1] - xi[5];
    float cr = xr[3] + xr[7], ci = xi[3] + xi[7];
    float dr = xr[3] - xr[7], di = xi[3] - xi[7];
    float O0r = ar + cr, O0i = ai + ci;
    float O2r = ar - cr, O2i = ai - ci;
    float O1r, O1i, O3r, O3i;
    if (SIGN < 0) { O1r = br + di; O1i = bi - dr; O3r = br - di; O3i = bi + dr; }
    else          { O1r = br - di; O1i = bi + dr; O3r = br + di; O3i = bi - dr; }
    float t1r, t1i, t2r, t2i, t3r, t3i;
    if (SIGN < 0) {
        t1r = r2 * (O1r + O1i); t1i = r2 * (O1i - O1r);
        t2r = O2i;              t2i = -O2r;
        t3r = r2 * (O3i - O3r); t3i = -r2 * (O3r + O3i);
    } else {
        t1r = r2 * (O1r - O1i); t1i = r2 * (O1i + O1r);
        t2r = -O2i;             t2i = O2r;
        t3r = -r2 * (O3r + O3i); t3i = r2 * (O3r - O3i);
    }
    yr[0] = E0r + O0r; yi[0] = E0i + O0i;  yr[4] = E0r - O0r; yi[4] = E0i - O0i;
    yr[1] = E1r + t1r; yi[1] = E1i + t1i;  yr[5] = E1r - t1r; yi[5] = E1i - t1i;
    yr[2] = E2r + t2r; yi[2] = E2i + t2i;  yr[6] = E2r - t2r; yi[6] = E2i - t2i;
    yr[3] = E3r + t3r; yi[3] = E3i + t3i;  yr[7] = E3r - t3r; yi[7] = E3i - t3i;
}

template <int SIGN, int S>
__device__ __forceinline__ void stage_write(float* lre, float* lim,
                                            const float yr[8], const float yi[8],
                                            int lane, const float2* __restrict__ tw)
{
    const int q = lane & (S - 1);
    const int p = lane / S;
    const int e = p * S;
    const int base = q + 8 * S * p;
#pragma unroll
    for (int j = 0; j < 8; ++j) {
        float vr = yr[j], vi = yi[j];
        if (j > 0) {
            float2 w = tw[j * e];
            float wr = w.x, wi = (SIGN < 0) ? w.y : -w.y;
            float tr = vr * wr - vi * wi;
            vi = vr * wi + vi * wr;
            vr = tr;
        }
        int o = LDSIDX(base + S * j);
        lre[o] = vr; lim[o] = vi;
    }
}

__device__ __forceinline__ void stage_read(const float* lre, const float* lim,
                                           float xr[8], float xi[8], int lane)
{
#pragma unroll
    for (int j = 0; j < 8; ++j) {
        int o = LDSIDX(lane + 64 * j);
        xr[j] = lre[o]; xi[j] = lim[o];
    }
}

// 512-pt FFT, 3 radix-8 stages, in-place per-wave LDS scratch, wave-local sync.
template <int SIGN>
__device__ __forceinline__ void fft512(float* lre, float* lim,
                                       float xr[8], float xi[8],
                                       float yr[8], float yi[8],
                                       int lane, const float2* __restrict__ tw)
{
    dft8<SIGN>(xr, xi, yr, yi);
    stage_write<SIGN, 1>(lre, lim, yr, yi, lane, tw);
    wsync();
    stage_read(lre, lim, xr, xi, lane);
    wsync();
    dft8<SIGN>(xr, xi, yr, yi);
    stage_write<SIGN, 8>(lre, lim, yr, yi, lane, tw);
    wsync();
    stage_read(lre, lim, xr, xi, lane);
    dft8<SIGN>(xr, xi, yr, yi);           // stage2: p=0 → no twiddles, stays in regs
}

// ---------------------------------------------------------------------------
// Tables
// ---------------------------------------------------------------------------
__global__ void k_tables(float2* tw512, float2* twh, float* win, float* wscl)
{
    int i = blockIdx.x * blockDim.x + threadIdx.x;
    if (i < 512) {
        double t1 = -2.0 * M_PI * (double)i / 512.0;
        tw512[i] = make_float2((float)cos(t1), (float)sin(t1));
        double t2 = -2.0 * M_PI * (double)i / 1024.0;
        twh[i] = make_float2((float)cos(t2), (float)sin(t2));
    }
    if (i < 1024) {
        double w = 0.5 - 0.5 * cos(2.0 * M_PI * (double)i / 1024.0);
        win[i]  = (float)w;
        wscl[i] = (float)(w / 512.0);
    }
}

__global__ void k_wsq(const float* __restrict__ win, float* __restrict__ wsqinv)
{
    int t = blockIdx.x * blockDim.x + threadIdx.x;
    if (t >= YLEN) return;
    int fhi = t >> 8;
    int flo = fhi - 3; if (flo < 0) flo = 0;
    if (fhi > TFRAMES - 1) fhi = TFRAMES - 1;
    float acc = 0.f;
    for (int f = flo; f <= fhi; ++f) {
        float w = win[t - (f << 8)];
        acc += w * w;
    }
    float m = acc > 1e-8f ? acc : 1e-8f;
    wsqinv[t] = 1.0f / m;
}

__global__ void k_melinvT(const float* __restrict__ melinv, float* __restrict__ melinvT)
{
    int idx = blockIdx.x * blockDim.x + threadIdx.x;
    if (idx >= 80 * NBINS) return;
    int m = idx / NBINS, k = idx - m * NBINS;
    melinvT[idx] = melinv[k * 80 + m];
}

__global__ __launch_bounds__(256) void k_angT(const float* __restrict__ ang0,
                                              float* __restrict__ angT)
{
    __shared__ float tile[32][33];
    int kt = blockIdx.x * 32, tt = blockIdx.y * 32, b = blockIdx.z;
    int tx = threadIdx.x & 31, ty = threadIdx.x >> 5;
#pragma unroll
    for (int i = 0; i < 32; i += 8) {
        int k = kt + ty + i, t = tt + tx;
        if (k < NBINS) tile[ty + i][tx] = ang0[((size_t)b * NBINS + k) * 1024 + t];
    }
    __syncthreads();
#pragma unroll
    for (int i = 0; i < 32; i += 8) {
        int t = tt + ty + i, k = kt + tx;
        if (k < NBINS) angT[((size_t)b * 1024 + t) * NBINS + k] = tile[tx][ty + i];
    }
}

__global__ __launch_bounds__(256) void k_specinit(const float* __restrict__ mel,
                                                  const float* __restrict__ melinvT,
                                                  const float* __restrict__ angT,
                                                  float* __restrict__ mag,
                                                  float2* __restrict__ spec)
{
    int blk = blockIdx.x;
    int b = blk >> 10;
    int t = blk & 1023;
    int tid = threadIdx.x;
    __shared__ float em[80];
    if (tid < 80) em[tid] = expf(mel[((size_t)b * 80 + tid) * 1024 + t]);
    __syncthreads();
    size_t row = (size_t)blk * SROW;
    size_t arow = ((size_t)b * 1024 + t) * NBINS;
    for (int k = tid; k < NBINS; k += 256) {
        float s = 0.f;
#pragma unroll 8
        for (int m = 0; m < 80; ++m) s += melinvT[m * NBINS + k] * em[m];
        float mg = fabsf(s);
        float a = angT[arow + k];
        float sn, cn;
        sincospif(2.0f * a, &sn, &cn);
        mag[row + k] = mg;
        spec[row + k] = make_float2(mg * cn, mg * sn);
    }
}

// ---------------------------------------------------------------------------
// ISTFT half: 4 independent waves per block, one spec row each.
// Hermitian pre-twist done in REGISTERS (spec[k] and spec[512-k] both
// coalesced global loads) — no LDS staging. frames written windowed (+1/512).
// ---------------------------------------------------------------------------
__global__ __launch_bounds__(256) void k_ifft(const float2* __restrict__ spec,
                                              const float2* __restrict__ tw512,
                                              const float2* __restrict__ twh,
                                              const float* __restrict__ wscl,
                                              float* __restrict__ frames)
{
    __shared__ float scr[4][2][LDSBUF];
    int tid = threadIdx.x;
    int w = tid >> 6, lane = tid & 63;
    int blk = blockIdx.x * 4 + w;
    size_t row = (size_t)blk * SROW;
    float* lre = scr[w][0];
    float* lim = scr[w][1];

    float xr[8], xi[8], yr[8], yi[8];
#pragma unroll
    for (int r = 0; r < 8; ++r) {
        int k = lane + 64 * r;
        float2 v1 = spec[row + k];
        float2 v2 = spec[row + 512 - k];
        if (k == 0) { v1.y = 0.f; v2.y = 0.f; }   // drop imag of DC & Nyquist
        float Ar = 0.5f * (v1.x + v2.x), Ai = 0.5f * (v1.y - v2.y);
        float Sr = 0.5f * (v1.x - v2.x), Si = 0.5f * (v1.y + v2.y);
        float2 W = twh[k];
        float Xor = W.x * Sr + W.y * Si;          // conj(W)*S
        float Xoi = W.x * Si - W.y * Sr;
        xr[r] = Ar - Xoi;                         // A + i*Xo
        xi[r] = Ai + Xor;
    }
    fft512<1>(lre, lim, xr, xi, yr, yi, lane, tw512);
    size_t frow = (size_t)blk * 1024;
#pragma unroll
    for (int j = 0; j < 8; ++j) {
        int m = lane + 64 * j;
        float2 ws = *(const float2*)&wscl[2 * m];
        float2 o;
        o.x = yr[j] * ws.x;
        o.y = yi[j] * ws.y;
        *(float2*)&frames[frow + 2 * m] = o;
    }
}

// ---------------------------------------------------------------------------
// Overlap-add: audioR[b][t] = (sum of <=4 frames at t) * wsqinv[t], t in [0,YLEN).
// All frame reads coalesced (consecutive t -> consecutive addresses).
// ---------------------------------------------------------------------------
__global__ __launch_bounds__(256) void k_oa(const float* __restrict__ frames,
                                            const float* __restrict__ wsqinv,
                                            float* __restrict__ audioR)
{
    int t = blockIdx.x * 256 + threadIdx.x;     // gridDim.x = YLEN/256
    int b = blockIdx.y;
    const float* fb = frames + (size_t)b * (TFRAMES * 1024);
    int fhi = t >> 8;
    int flo = fhi - 3; if (flo < 0) flo = 0;
    if (fhi > TFRAMES - 1) fhi = TFRAMES - 1;
    float acc = 0.f;
    for (int ff = flo; ff <= fhi; ++ff)
        acc += fb[(size_t)ff * 1024 + (t - (ff << 8))];
    audioR[(size_t)b * YLEN + t] = acc * wsqinv[t];
}

// ---------------------------------------------------------------------------
// STFT half + GL phase update: 4 waves per block, one frame row each.
// Input window = 8 coalesced float2 loads from audioR (reflect only at edges).
// ---------------------------------------------------------------------------
__global__ __launch_bounds__(256) void k_fft(const float* __restrict__ audioR,
                                             const float* __restrict__ mag,
                                             const float2* __restrict__ tw512,
                                             const float2* __restrict__ twh,
                                             const float* __restrict__ win,
                                             float2* __restrict__ spec,
                                             float2* __restrict__ rebprev,
                                             float beta)
{
    __shared__ float scr[4][2][LDSBUF];
    int tid = threadIdx.x;
    int w = tid >> 6, lane = tid & 63;
    int blk = blockIdx.x * 4 + w;
    int b = blk >> 10;
    int f = blk & 1023;
    const float* ab = audioR + (size_t)b * YLEN;
    float* lre = scr[w][0];
    float* lim = scr[w][1];

    float xr[8], xi[8], yr[8], yi[8];
    if (f >= 2 && f <= 1021) {
        // interior: window [f*256, f*256+1023] maps 1:1 into audioR
        const float* src = ab + f * HOPSZ;
#pragma unroll
        for (int j = 0; j < 8; ++j) {
            int n0 = 2 * (lane + 64 * j);
            float2 s = *(const float2*)&src[n0];
            float2 w2 = *(const float2*)&win[n0];
            xr[j] = s.x * w2.x;
            xi[j] = s.y * w2.y;
        }
    } else {
#pragma unroll
        for (int j = 0; j < 8; ++j) {
            int n0 = 2 * (lane + 64 * j);
            int j0 = f * HOPSZ + n0 - 512;
            int ja = (j0 < 0) ? -j0 : ((j0 >= LOUT) ? 2 * LOUT - 2 - j0 : j0);
            int j1 = j0 + 1;
            int jb = (j1 < 0) ? -j1 : ((j1 >= LOUT) ? 2 * LOUT - 2 - j1 : j1);
            float s0 = ab[ja + 512];
            float s1 = ab[jb + 512];
            float2 w2 = *(const float2*)&win[n0];
            xr[j] = s0 * w2.x;
            xi[j] = s1 * w2.y;
        }
    }
    fft512<-1>(lre, lim, xr, xi, yr, yi, lane, tw512);
    // Z to LDS for the cross-lane Hermitian post-twist
#pragma unroll
    for (int j = 0; j < 8; ++j) {
        int o = LDSIDX(lane + 64 * j);
        lre[o] = yr[j]; lim[o] = yi[j];
    }
    wsync();
    size_t row = (size_t)blk * SROW;
#pragma unroll
    for (int rr = 0; rr < 9; ++rr) {
        int k;
        if (rr < 8) k = lane + 64 * rr;
        else { if (lane != 0) break; k = 512; }
        int kk = k & 511, mm = (512 - k) & 511;
        float Zkr = lre[LDSIDX(kk)], Zki = lim[LDSIDX(kk)];
        float Zmr = lre[LDSIDX(mm)], Zmi = lim[LDSIDX(mm)];
        float Ar = 0.5f * (Zkr + Zmr), Ai = 0.5f * (Zki - Zmi);
        float Sr = 0.5f * (Zkr - Zmr), Si = 0.5f * (Zki + Zmi);
        float wr_, wi_;
        if (k == 512) { wr_ = -1.f; wi_ = 0.f; }
        else { float2 W = twh[k]; wr_ = W.x; wi_ = W.y; }
        float Ur = wr_ * Sr - wi_ * Si;
        float Ui = wr_ * Si + wi_ * Sr;
        float Xr = Ar + Ui;                   // A - i*(W*S)
        float Xi = Ai - Ur;
        float2 pv = rebprev[row + k];
        float vx = Xr - beta * pv.x;
        float vy = Xi - beta * pv.y;
        float a = sqrtf(vx * vx + vy * vy) + 1e-16f;
        float sc = mag[row + k] / a;
        spec[row + k] = make_float2(vx * sc, vy * sc);
        rebprev[row + k] = make_float2(Xr, Xi);
    }
}

// Final overlap-add -> audio out (crop 512 each side)
__global__ __launch_bounds__(256) void k_gather(const float* __restrict__ frames,
                                                const float* __restrict__ wsqinv,
                                                float* __restrict__ out)
{
    int idx = blockIdx.x * 256 + threadIdx.x;
    if (idx >= BATCH * LOUT) return;
    int b = idx / LOUT;
    int j = idx - b * LOUT;
    int t = j + 512;
    const float* fb = frames + (size_t)b * (TFRAMES * 1024);
    int fhi = t >> 8;
    int flo = fhi - 3; if (flo < 0) flo = 0;
    if (fhi > TFRAMES - 1) fhi = TFRAMES - 1;
    float acc = 0.f;
    for (int ff = flo; ff <= fhi; ++ff)
        acc += fb[(size_t)ff * 1024 + (t - (ff << 8))];
    out[idx] = acc * wsqinv[t];
}

// ---------------------------------------------------------------------------
extern "C" void kernel_launch(void* const* d_in, const int* in_sizes, int n_in,
                              void* d_out, int out_size, void* d_ws, size_t ws_size,
                              hipStream_t stream)
{
    const float* mel    = (const float*)d_in[0];   // [8, 80, 1024]
    const float* melinv = (const float*)d_in[1];   // [513, 80]
    const float* ang0   = (const float*)d_in[2];   // [8, 513, 1024]
    float* out = (float*)d_out;                    // [8, 261888]

    char* ws = (char*)d_ws;
    size_t off = 0;
    auto carve = [&](size_t bytes) -> void* {
        void* p = ws + off;
        off += (bytes + 255) & ~(size_t)255;
        return p;
    };
    float2* tw512   = (float2*)carve(512 * sizeof(float2));
    float2* twh     = (float2*)carve(512 * sizeof(float2));
    float*  win     = (float*) carve(1024 * sizeof(float));
    float*  wscl    = (float*) carve(1024 * sizeof(float));
    float*  wsqinv  = (float*) carve((size_t)YLEN * sizeof(float));
    float*  melinvT = (float*) carve((size_t)80 * NBINS * sizeof(float));
    float*  mag     = (float*) carve((size_t)NBLK * SROW * sizeof(float));
    float2* spec    = (float2*)carve((size_t)NBLK * SROW * sizeof(float2));
    float2* rebp    = (float2*)carve((size_t)NBLK * SROW * sizeof(float2));
    float*  frames  = (float*) carve((size_t)NBLK * 1024 * sizeof(float));
    float*  audioR  = (float*) carve((size_t)BATCH * YLEN * sizeof(float));
    float*  angT    = frames;  // alias: angT consumed by k_specinit before any k_ifft
    (void)ws_size; (void)in_sizes; (void)n_in; (void)out_size;

    const float beta = (float)(0.99 / 1.99);

    hipLaunchKernelGGL(k_tables, dim3(4), dim3(256), 0, stream, tw512, twh, win, wscl);
    hipLaunchKernelGGL(k_wsq, dim3((YLEN + 255) / 256), dim3(256), 0, stream, win, wsqinv);
    hipLaunchKernelGGL(k_melinvT, dim3((80 * NBINS + 255) / 256), dim3(256), 0, stream,
                       melinv, melinvT);
    hipLaunchKernelGGL(k_angT, dim3(17, 32, BATCH), dim3(256), 0, stream, ang0, angT);
    hipLaunchKernelGGL(k_specinit, dim3(NBLK), dim3(256), 0, stream,
                       mel, melinvT, angT, mag, spec);
    (void)hipMemsetAsync(rebp, 0, (size_t)NBLK * SROW * sizeof(float2), stream);

    for (int it = 0; it < NITER; ++it) {
        hipLaunchKernelGGL(k_ifft, dim3(NBLK / 4), dim3(256), 0, stream,
                           spec, tw512, twh, wscl, frames);
        hipLaunchKernelGGL(k_oa, dim3(YLEN / 256, BATCH), dim3(256), 0, stream,
                           frames, wsqinv, audioR);
        hipLaunchKernelGGL(k_fft, dim3(NBLK / 4), dim3(256), 0, stream,
                           audioR, mag, tw512, twh, win, spec, rebp, beta);
    }
    hipLaunchKernelGGL(k_ifft, dim3(NBLK / 4), dim3(256), 0, stream,
                       spec, tw512, twh, wscl, frames);
    hipLaunchKernelGGL(k_gather, dim3((BATCH * LOUT + 255) / 256), dim3(256), 0, stream,
                       frames, wsqinv, out);
}

// Round 5
// 1398.484 us; speedup vs baseline: 1.9971x; 1.5027x over previous
//
#include <hip/hip_runtime.h>
#include <math.h>

// Problem constants (match reference)
#define BATCH    8
#define NFFT     1024
#define HOPSZ    256
#define NBINS    513        // NFFT/2 + 1
#define SROW     516        // padded row stride (elements) for spec/mag/rebprev rows
#define TFRAMES  1024       // frames per batch (== T)
#define NBLK     (BATCH * TFRAMES)     // 8192 rows
#define LOUT     261888     // HOP*(T-1) : audio length per batch
#define YLEN     262912     // NFFT + HOP*(TFRAMES-1) = 1027*256
#define NITER    32

// LDS skew: physical = i + i/32 → breaks power-of-2 stride bank conflicts
#define LDSIDX(i) ((i) + ((i) >> 5))
#define LDSBUF    532       // LDSIDX(512)=528 + headroom

// Wave-local LDS sync: per-wave scratch only, DS ops within a wave complete
// in order; this replaces __syncthreads (validated rounds 2-4).
__device__ __forceinline__ void wsync() {
    __asm__ volatile("s_waitcnt lgkmcnt(0)" ::: "memory");
}

// ---------------------------------------------------------------------------
// 8-point DFT in registers. SIGN=-1 forward, +1 inverse (unscaled).
// ---------------------------------------------------------------------------
template <int SIGN>
__device__ __forceinline__ void dft8(const float xr[8], const float xi[8],
                                     float yr[8], float yi[8])
{
    const float r2 = 0.70710678118654752f;
    float Ar = xr[0] + xr[4], Ai = xi[0] + xi[4];
    float Br = xr[0] - xr[4], Bi = xi[0] - xi[4];
    float Cr = xr[2] + xr[6], Ci = xi[2] + xi[6];
    float Dr = xr[2] - xr[6], Di = xi[2] - xi[6];
    float E0r = Ar + Cr, E0i = Ai + Ci;
    float E2r = Ar - Cr, E2i = Ai - Ci;
    float E1r, E1i, E3r, E3i;
    if (SIGN < 0) { E1r = Br + Di; E1i = Bi - Dr; E3r = Br - Di; E3i = Bi + Dr; }
    else          { E1r = Br - Di; E1i = Bi + Dr; E3r = Br + Di; E3i = Bi - Dr; }
    float ar = xr[1] + xr[5], ai = xi[1] + xi[5];
    float br = xr[1] - xr[5], bi = xi[1] - xi[5];
    float cr = xr[3] + xr[7], ci = xi[3] + xi[7];
    float dr = xr[3] - xr[7], di = xi[3] - xi[7];
    float O0r = ar + cr, O0i = ai + ci;
    float O2r = ar - cr, O2i = ai - ci;
    float O1r, O1i, O3r, O3i;
    if (SIGN < 0) { O1r = br + di; O1i = bi - dr; O3r = br - di; O3i = bi + dr; }
    else          { O1r = br - di; O1i = bi + dr; O3r = br + di; O3i = bi - dr; }
    float t1r, t1i, t2r, t2i, t3r, t3i;
    if (SIGN < 0) {
        t1r = r2 * (O1r + O1i); t1i = r2 * (O1i - O1r);
        t2r = O2i;              t2i = -O2r;
        t3r = r2 * (O3i - O3r); t3i = -r2 * (O3r + O3i);
    } else {
        t1r = r2 * (O1r - O1i); t1i = r2 * (O1i + O1r);
        t2r = -O2i;             t2i = O2r;
        t3r = -r2 * (O3r + O3i); t3i = r2 * (O3r - O3i);
    }
    yr[0] = E0r + O0r; yi[0] = E0i + O0i;  yr[4] = E0r - O0r; yi[4] = E0i - O0i;
    yr[1] = E1r + t1r; yi[1] = E1i + t1i;  yr[5] = E1r - t1r; yi[5] = E1i - t1i;
    yr[2] = E2r + t2r; yi[2] = E2i + t2i;  yr[6] = E2r - t2r; yi[6] = E2i - t2i;
    yr[3] = E3r + t3r; yi[3] = E3i + t3i;  yr[7] = E3r - t3r; yi[7] = E3i - t3i;
}

template <int SIGN, int S>
__device__ __forceinline__ void stage_write(float* lre, float* lim,
                                            const float yr[8], const float yi[8],
                                            int lane, const float2* __restrict__ tw)
{
    const int q = lane & (S - 1);
    const int p = lane / S;
    const int e = p * S;
    const int base = q + 8 * S * p;
#pragma unroll
    for (int j = 0; j < 8; ++j) {
        float vr = yr[j], vi = yi[j];
        if (j > 0) {
            float2 w = tw[j * e];
            float wr = w.x, wi = (SIGN < 0) ? w.y : -w.y;
            float tr = vr * wr - vi * wi;
            vi = vr * wi + vi * wr;
            vr = tr;
        }
        int o = LDSIDX(base + S * j);
        lre[o] = vr; lim[o] = vi;
    }
}

__device__ __forceinline__ void stage_read(const float* lre, const float* lim,
                                           float xr[8], float xi[8], int lane)
{
#pragma unroll
    for (int j = 0; j < 8; ++j) {
        int o = LDSIDX(lane + 64 * j);
        xr[j] = lre[o]; xi[j] = lim[o];
    }
}

// 512-pt FFT, 3 radix-8 stages, in-place per-wave LDS scratch, wave-local sync.
// Stage-0 input in regs (positions lane+64j); output in yr/yi (same positions).
template <int SIGN>
__device__ __forceinline__ void fft512(float* lre, float* lim,
                                       float xr[8], float xi[8],
                                       float yr[8], float yi[8],
                                       int lane, const float2* __restrict__ tw)
{
    dft8<SIGN>(xr, xi, yr, yi);
    stage_write<SIGN, 1>(lre, lim, yr, yi, lane, tw);
    wsync();
    stage_read(lre, lim, xr, xi, lane);
    wsync();
    dft8<SIGN>(xr, xi, yr, yi);
    stage_write<SIGN, 8>(lre, lim, yr, yi, lane, tw);
    wsync();
    stage_read(lre, lim, xr, xi, lane);
    dft8<SIGN>(xr, xi, yr, yi);           // stage2: p=0 → no twiddles, stays in regs
}

// Variant with stage-0 input already in LDS (positions lane+64j).
template <int SIGN>
__device__ __forceinline__ void fft512_lds(float* lre, float* lim,
                                           float xr[8], float xi[8],
                                           float yr[8], float yi[8],
                                           int lane, const float2* __restrict__ tw)
{
    stage_read(lre, lim, xr, xi, lane);
    wsync();
    fft512<SIGN>(lre, lim, xr, xi, yr, yi, lane, tw);
}

// ---------------------------------------------------------------------------
// Tables
// ---------------------------------------------------------------------------
__global__ void k_tables(float2* tw512, float2* twh, float* win, float* wscl)
{
    int i = blockIdx.x * blockDim.x + threadIdx.x;
    if (i < 512) {
        double t1 = -2.0 * M_PI * (double)i / 512.0;
        tw512[i] = make_float2((float)cos(t1), (float)sin(t1));
        double t2 = -2.0 * M_PI * (double)i / 1024.0;
        twh[i] = make_float2((float)cos(t2), (float)sin(t2));
    }
    if (i < 1024) {
        double w = 0.5 - 0.5 * cos(2.0 * M_PI * (double)i / 1024.0);
        win[i]  = (float)w;
        wscl[i] = (float)(w / 512.0);
    }
}

__global__ void k_wsq(const float* __restrict__ win, float* __restrict__ wsqinv)
{
    int t = blockIdx.x * blockDim.x + threadIdx.x;
    if (t >= YLEN) return;
    int fhi = t >> 8;
    int flo = fhi - 3; if (flo < 0) flo = 0;
    if (fhi > TFRAMES - 1) fhi = TFRAMES - 1;
    float acc = 0.f;
    for (int f = flo; f <= fhi; ++f) {
        float w = win[t - (f << 8)];
        acc += w * w;
    }
    float m = acc > 1e-8f ? acc : 1e-8f;
    wsqinv[t] = 1.0f / m;
}

__global__ void k_melinvT(const float* __restrict__ melinv, float* __restrict__ melinvT)
{
    int idx = blockIdx.x * blockDim.x + threadIdx.x;
    if (idx >= 80 * NBINS) return;
    int m = idx / NBINS, k = idx - m * NBINS;
    melinvT[idx] = melinv[k * 80 + m];
}

__global__ __launch_bounds__(256) void k_angT(const float* __restrict__ ang0,
                                              float* __restrict__ angT)
{
    __shared__ float tile[32][33];
    int kt = blockIdx.x * 32, tt = blockIdx.y * 32, b = blockIdx.z;
    int tx = threadIdx.x & 31, ty = threadIdx.x >> 5;
#pragma unroll
    for (int i = 0; i < 32; i += 8) {
        int k = kt + ty + i, t = tt + tx;
        if (k < NBINS) tile[ty + i][tx] = ang0[((size_t)b * NBINS + k) * 1024 + t];
    }
    __syncthreads();
#pragma unroll
    for (int i = 0; i < 32; i += 8) {
        int t = tt + ty + i, k = kt + tx;
        if (k < NBINS) angT[((size_t)b * 1024 + t) * NBINS + k] = tile[tx][ty + i];
    }
}

__global__ __launch_bounds__(256) void k_specinit(const float* __restrict__ mel,
                                                  const float* __restrict__ melinvT,
                                                  const float* __restrict__ angT,
                                                  float* __restrict__ mag,
                                                  float2* __restrict__ spec)
{
    int blk = blockIdx.x;
    int b = blk >> 10;
    int t = blk & 1023;
    int tid = threadIdx.x;
    __shared__ float em[80];
    if (tid < 80) em[tid] = expf(mel[((size_t)b * 80 + tid) * 1024 + t]);
    __syncthreads();
    size_t row = (size_t)blk * SROW;
    size_t arow = ((size_t)b * 1024 + t) * NBINS;
    for (int k = tid; k < NBINS; k += 256) {
        float s = 0.f;
#pragma unroll 8
        for (int m = 0; m < 80; ++m) s += melinvT[m * NBINS + k] * em[m];
        float mg = fabsf(s);
        float a = angT[arow + k];
        float sn, cn;
        sincospif(2.0f * a, &sn, &cn);
        mag[row + k] = mg;
        spec[row + k] = make_float2(mg * cn, mg * sn);
    }
}

// ---------------------------------------------------------------------------
// Initial ISTFT half (reads global spec = Sc*angles0): 4 waves/block, one row
// each, Hermitian pre-twist in registers. frames written windowed (+1/512).
// ---------------------------------------------------------------------------
__global__ __launch_bounds__(256) void k_ifft(const float2* __restrict__ spec,
                                              const float2* __restrict__ tw512,
                                              const float2* __restrict__ twh,
                                              const float* __restrict__ wscl,
                                              float* __restrict__ frames)
{
    __shared__ float scr[4][2][LDSBUF];
    int tid = threadIdx.x;
    int w = tid >> 6, lane = tid & 63;
    int blk = blockIdx.x * 4 + w;
    size_t row = (size_t)blk * SROW;
    float* lre = scr[w][0];
    float* lim = scr[w][1];

    float xr[8], xi[8], yr[8], yi[8];
#pragma unroll
    for (int r = 0; r < 8; ++r) {
        int k = lane + 64 * r;
        float2 v1 = spec[row + k];
        float2 v2 = spec[row + 512 - k];
        if (k == 0) { v1.y = 0.f; v2.y = 0.f; }   // drop imag of DC & Nyquist
        float Ar = 0.5f * (v1.x + v2.x), Ai = 0.5f * (v1.y - v2.y);
        float Sr = 0.5f * (v1.x - v2.x), Si = 0.5f * (v1.y + v2.y);
        float2 W = twh[k];
        float Xor = W.x * Sr + W.y * Si;          // conj(W)*S
        float Xoi = W.x * Si - W.y * Sr;
        xr[r] = Ar - Xoi;                         // A + i*Xo
        xi[r] = Ai + Xor;
    }
    fft512<1>(lre, lim, xr, xi, yr, yi, lane, tw512);
    size_t frow = (size_t)blk * 1024;
#pragma unroll
    for (int j = 0; j < 8; ++j) {
        int m = lane + 64 * j;
        float2 ws = *(const float2*)&wscl[2 * m];
        float2 o;
        o.x = yr[j] * ws.x;
        o.y = yi[j] * ws.y;
        *(float2*)&frames[frow + 2 * m] = o;
    }
}

// ---------------------------------------------------------------------------
// Overlap-add: audioR[b][t] = (sum of <=4 frames at t) * wsqinv[t].
// ---------------------------------------------------------------------------
__global__ __launch_bounds__(256) void k_oa(const float* __restrict__ frames,
                                            const float* __restrict__ wsqinv,
                                            float* __restrict__ audioR)
{
    int t = blockIdx.x * 256 + threadIdx.x;     // gridDim.x = YLEN/256
    int b = blockIdx.y;
    const float* fb = frames + (size_t)b * (TFRAMES * 1024);
    int fhi = t >> 8;
    int flo = fhi - 3; if (flo < 0) flo = 0;
    if (fhi > TFRAMES - 1) fhi = TFRAMES - 1;
    float acc = 0.f;
    for (int ff = flo; ff <= fhi; ++ff)
        acc += fb[(size_t)ff * 1024 + (t - (ff << 8))];
    audioR[(size_t)b * YLEN + t] = acc * wsqinv[t];
}

// ---------------------------------------------------------------------------
// FUSED: STFT + Griffin-Lim phase update + ISTFT, one frame row per wave.
// The spectrum never touches global memory: after the forward FFT the
// Hermitian post-twist, GL update, and Hermitian pre-twist are done as an
// in-place LDS pair pass — pair (p, 512-p) reads Z[p],Z[512-p] and writes
// Z'[p],Z'[512-p] into the SAME slots (all pairs slot-disjoint → no hazard).
// ---------------------------------------------------------------------------
__global__ __launch_bounds__(256) void k_fused(const float* __restrict__ audioR,
                                               const float* __restrict__ mag,
                                               const float2* __restrict__ tw512,
                                               const float2* __restrict__ twh,
                                               const float* __restrict__ win,
                                               const float* __restrict__ wscl,
                                               float2* __restrict__ rebprev,
                                               float* __restrict__ frames,
                                               float beta)
{
    __shared__ float scr[4][2][LDSBUF];
    int tid = threadIdx.x;
    int w = tid >> 6, lane = tid & 63;
    int blk = blockIdx.x * 4 + w;
    int b = blk >> 10;
    int f = blk & 1023;
    const float* ab = audioR + (size_t)b * YLEN;
    float* lre = scr[w][0];
    float* lim = scr[w][1];

    // ---- forward FFT input: windowed frame (coalesced interior fast path) ----
    float xr[8], xi[8], yr[8], yi[8];
    if (f >= 2 && f <= 1021) {
        const float* src = ab + f * HOPSZ;
#pragma unroll
        for (int j = 0; j < 8; ++j) {
            int n0 = 2 * (lane + 64 * j);
            float2 s = *(const float2*)&src[n0];
            float2 w2 = *(const float2*)&win[n0];
            xr[j] = s.x * w2.x;
            xi[j] = s.y * w2.y;
        }
    } else {
#pragma unroll
        for (int j = 0; j < 8; ++j) {
            int n0 = 2 * (lane + 64 * j);
            int j0 = f * HOPSZ + n0 - 512;
            int ja = (j0 < 0) ? -j0 : ((j0 >= LOUT) ? 2 * LOUT - 2 - j0 : j0);
            int j1 = j0 + 1;
            int jb = (j1 < 0) ? -j1 : ((j1 >= LOUT) ? 2 * LOUT - 2 - j1 : j1);
            float s0 = ab[ja + 512];
            float s1 = ab[jb + 512];
            float2 w2 = *(const float2*)&win[n0];
            xr[j] = s0 * w2.x;
            xi[j] = s1 * w2.y;
        }
    }
    fft512<-1>(lre, lim, xr, xi, yr, yi, lane, tw512);

    // ---- Z to LDS ----
#pragma unroll
    for (int j = 0; j < 8; ++j) {
        int o = LDSIDX(lane + 64 * j);
        lre[o] = yr[j]; lim[o] = yi[j];
    }
    wsync();

    // ---- in-place pair pass: post-twist → GL update → pre-twist ----
    size_t row = (size_t)blk * SROW;
#pragma unroll
    for (int r = 0; r < 5; ++r) {
        int p;
        if (r < 4) p = lane + 64 * r;          // p in [0,255]
        else { if (lane != 0) break; p = 256; }  // self-paired center bin
        int pm = (512 - p) & 511;              // mirror Z slot (p=0 → 0)
        float Zkr = lre[LDSIDX(p)],  Zki = lim[LDSIDX(p)];
        float Zmr = lre[LDSIDX(pm)], Zmi = lim[LDSIDX(pm)];
        float Ar = 0.5f * (Zkr + Zmr), Ai = 0.5f * (Zki - Zmi);
        float Sr = 0.5f * (Zkr - Zmr), Si = 0.5f * (Zki + Zmi);
        // X[p] = A + i*conj-combine with W1 = twh[p]
        float2 W1 = twh[p];
        float U1r = W1.x * Sr - W1.y * Si, U1i = W1.x * Si + W1.y * Sr;
        float Xpr = Ar + U1i, Xpi = Ai - U1r;
        // X[512-p]: A2 = (Ar,-Ai), S2 = (-Sr,Si), W2 = twh[512-p] (p=0 → -1)
        float w2r, w2i;
        if (p == 0) { w2r = -1.f; w2i = 0.f; }
        else { float2 W2 = twh[512 - p]; w2r = W2.x; w2i = W2.y; }
        float U2r = -w2r * Sr - w2i * Si, U2i = w2r * Si - w2i * Sr;
        float Xqr = Ar + U2i, Xqi = -Ai - U2r;
        // GL update at k=p and k=512-p
        int q = 512 - p;
        float2 pv1 = rebprev[row + p];
        float2 pv2 = rebprev[row + q];
        float v1x = Xpr - beta * pv1.x, v1y = Xpi - beta * pv1.y;
        float v2x = Xqr - beta * pv2.x, v2y = Xqi - beta * pv2.y;
        float a1 = sqrtf(v1x * v1x + v1y * v1y) + 1e-16f;
        float a2 = sqrtf(v2x * v2x + v2y * v2y) + 1e-16f;
        float sc1 = mag[row + p] / a1;
        float sc2 = mag[row + q] / a2;
        float s1x = v1x * sc1, s1y = v1y * sc1;   // spec[p]
        float s2x = v2x * sc2, s2y = v2y * sc2;   // spec[512-p]
        rebprev[row + p] = make_float2(Xpr, Xpi);
        rebprev[row + q] = make_float2(Xqr, Xqi);
        // pre-twist Z'[p]: v1=s1, v2=s2, W=W1
        float Apr = 0.5f * (s1x + s2x), Api = 0.5f * (s1y - s2y);
        float Spr = 0.5f * (s1x - s2x), Spi = 0.5f * (s1y + s2y);
        float Xor = W1.x * Spr + W1.y * Spi;
        float Xoi = W1.x * Spi - W1.y * Spr;
        lre[LDSIDX(p)] = Apr - Xoi;
        lim[LDSIDX(p)] = Api + Xor;
        if (p > 0) {
            // Z'[512-p]: v1=s2, v2=s1 → A=(Apr,-Api), S=(-Spr,Spi), W=(w2r,w2i)
            float Yor = -w2r * Spr + w2i * Spi;
            float Yoi = w2r * Spi + w2i * Spr;
            lre[LDSIDX(512 - p)] = Apr - Yoi;
            lim[LDSIDX(512 - p)] = -Api + Yor;
        }
    }
    wsync();

    // ---- inverse FFT from LDS, write windowed frames ----
    fft512_lds<1>(lre, lim, xr, xi, yr, yi, lane, tw512);
    size_t frow = (size_t)blk * 1024;
#pragma unroll
    for (int j = 0; j < 8; ++j) {
        int m = lane + 64 * j;
        float2 ws = *(const float2*)&wscl[2 * m];
        float2 o;
        o.x = yr[j] * ws.x;
        o.y = yi[j] * ws.y;
        *(float2*)&frames[frow + 2 * m] = o;
    }
}

// Final overlap-add -> audio out (crop 512 each side)
__global__ __launch_bounds__(256) void k_gather(const float* __restrict__ frames,
                                                const float* __restrict__ wsqinv,
                                                float* __restrict__ out)
{
    int idx = blockIdx.x * 256 + threadIdx.x;
    if (idx >= BATCH * LOUT) return;
    int b = idx / LOUT;
    int j = idx - b * LOUT;
    int t = j + 512;
    const float* fb = frames + (size_t)b * (TFRAMES * 1024);
    int fhi = t >> 8;
    int flo = fhi - 3; if (flo < 0) flo = 0;
    if (fhi > TFRAMES - 1) fhi = TFRAMES - 1;
    float acc = 0.f;
    for (int ff = flo; ff <= fhi; ++ff)
        acc += fb[(size_t)ff * 1024 + (t - (ff << 8))];
    out[idx] = acc * wsqinv[t];
}

// ---------------------------------------------------------------------------
extern "C" void kernel_launch(void* const* d_in, const int* in_sizes, int n_in,
                              void* d_out, int out_size, void* d_ws, size_t ws_size,
                              hipStream_t stream)
{
    const float* mel    = (const float*)d_in[0];   // [8, 80, 1024]
    const float* melinv = (const float*)d_in[1];   // [513, 80]
    const float* ang0   = (const float*)d_in[2];   // [8, 513, 1024]
    float* out = (float*)d_out;                    // [8, 261888]

    char* ws = (char*)d_ws;
    size_t off = 0;
    auto carve = [&](size_t bytes) -> void* {
        void* p = ws + off;
        off += (bytes + 255) & ~(size_t)255;
        return p;
    };
    float2* tw512   = (float2*)carve(512 * sizeof(float2));
    float2* twh     = (float2*)carve(512 * sizeof(float2));
    float*  win     = (float*) carve(1024 * sizeof(float));
    float*  wscl    = (float*) carve(1024 * sizeof(float));
    float*  wsqinv  = (float*) carve((size_t)YLEN * sizeof(float));
    float*  melinvT = (float*) carve((size_t)80 * NBINS * sizeof(float));
    float*  mag     = (float*) carve((size_t)NBLK * SROW * sizeof(float));
    float2* spec    = (float2*)carve((size_t)NBLK * SROW * sizeof(float2));
    float2* rebp    = (float2*)carve((size_t)NBLK * SROW * sizeof(float2));
    float*  frames  = (float*) carve((size_t)NBLK * 1024 * sizeof(float));
    float*  audioR  = (float*) carve((size_t)BATCH * YLEN * sizeof(float));
    float*  angT    = frames;  // alias: angT consumed by k_specinit before any k_ifft
    (void)ws_size; (void)in_sizes; (void)n_in; (void)out_size;

    const float beta = (float)(0.99 / 1.99);

    hipLaunchKernelGGL(k_tables, dim3(4), dim3(256), 0, stream, tw512, twh, win, wscl);
    hipLaunchKernelGGL(k_wsq, dim3((YLEN + 255) / 256), dim3(256), 0, stream, win, wsqinv);
    hipLaunchKernelGGL(k_melinvT, dim3((80 * NBINS + 255) / 256), dim3(256), 0, stream,
                       melinv, melinvT);
    hipLaunchKernelGGL(k_angT, dim3(17, 32, BATCH), dim3(256), 0, stream, ang0, angT);
    hipLaunchKernelGGL(k_specinit, dim3(NBLK), dim3(256), 0, stream,
                       mel, melinvT, angT, mag, spec);
    (void)hipMemsetAsync(rebp, 0, (size_t)NBLK * SROW * sizeof(float2), stream);

    // Initial ISTFT of Sc*angles0
    hipLaunchKernelGGL(k_ifft, dim3(NBLK / 4), dim3(256), 0, stream,
                       spec, tw512, twh, wscl, frames);
    // 32 fused GL iterations; after the last one `frames` holds the final ISTFT
    for (int it = 0; it < NITER; ++it) {
        hipLaunchKernelGGL(k_oa, dim3(YLEN / 256, BATCH), dim3(256), 0, stream,
                           frames, wsqinv, audioR);
        hipLaunchKernelGGL(k_fused, dim3(NBLK / 4), dim3(256), 0, stream,
                           audioR, mag, tw512, twh, win, wscl, rebp, frames, beta);
    }
    hipLaunchKernelGGL(k_gather, dim3((BATCH * LOUT + 255) / 256), dim3(256), 0, stream,
                       frames, wsqinv, out);
}